// Round 1
// baseline (7200.656 us; speedup 1.0000x reference)
//
#include <hip/hip_runtime.h>
#include <math.h>

// Problem constants
#define T_SEQ 12
// B=1024, NG=32, G=32, E=64, H=128, PP=512, BOT=1024, MLPD=1024

// Workspace layout (float offsets)
enum : int {
  OFF_LP   = 0,        // [1024,2]
  OFF_DIN  = 2048,     // [1024,64]
  OFF_HDEC = 67584,    // [1024,128]
  OFF_C    = 198656,   // [1024,128]
  OFF_HL   = 329728,   // [1024,128]
  OFF_WC   = 460800,   // [2,512]
  OFF_BC   = 461824,   // [512]
  OFF_PW   = 462336,   // [1024,512]
  OFF_AA   = 986624,   // [1024,512]
  OFF_POOL = 1510912,  // [1024,1024]
  OFF_MID  = 2559488   // [1024,1024]
};                     // total 3608064 floats = 14.4 MB

__global__ __launch_bounds__(256) void k_setup(
    const float* __restrict__ last_pos, const float* __restrict__ lpr,
    const float* __restrict__ dh, const float* __restrict__ dc,
    const float* __restrict__ W_emb, const float* __restrict__ b_emb,
    float* __restrict__ lp, float* __restrict__ din,
    float* __restrict__ h_dec, float* __restrict__ c) {
  int idx = blockIdx.x * 256 + threadIdx.x;  // 0..131071
  if (idx < 2048) lp[idx] = last_pos[idx];
  h_dec[idx] = dh[idx];
  c[idx] = dc[idx];
  if (idx < 65536) {
    int b = idx >> 6, e = idx & 63;
    din[idx] = lpr[b*2] * W_emb[e] + lpr[b*2+1] * W_emb[64+e] + b_emb[e];
  }
}

// Wc[r][n] = sum_k W_sp[r,k] * W_pp1[k,n];  bc[n] = sum_k b_sp[k]*W_pp1[k,n] + b_pp1[n]
__global__ __launch_bounds__(256) void k_wc(
    const float* __restrict__ W_sp, const float* __restrict__ b_sp,
    const float* __restrict__ W_pp1, const float* __restrict__ b_pp1,
    float* __restrict__ Wc, float* __restrict__ bc) {
  int n = blockIdx.x * 256 + threadIdx.x;
  if (n >= 512) return;
  float a0 = 0.f, a1 = 0.f, ab = 0.f;
#pragma unroll 8
  for (int k = 0; k < 64; k++) {
    float w = W_pp1[k*512 + n];
    a0 += W_sp[k] * w;
    a1 += W_sp[64+k] * w;
    ab += b_sp[k] * w;
  }
  Wc[n] = a0; Wc[512+n] = a1; bc[n] = ab + b_pp1[n];
}

// LSTM cell: one block per batch row, 128 threads (one per h-dim)
__global__ __launch_bounds__(128) void k_lstm(
    const float* __restrict__ din, const float* __restrict__ h_dec,
    float* __restrict__ c, float* __restrict__ h_lstm,
    const float* __restrict__ W_ih, const float* __restrict__ b_ih,
    const float* __restrict__ W_hh, const float* __restrict__ b_hh) {
  int b = blockIdx.x, t = threadIdx.x;
  __shared__ float xh[192];
  if (t < 64) xh[t] = din[b*64 + t];
  xh[64 + t] = h_dec[b*128 + t];
  __syncthreads();
  float g4[4];
#pragma unroll
  for (int q = 0; q < 4; q++) {
    int n = q*128 + t;
    float acc = b_ih[n] + b_hh[n];
    const float4* wi = (const float4*)(W_ih + n*64);
#pragma unroll 4
    for (int k4 = 0; k4 < 16; k4++) {
      float4 w = wi[k4];
      acc += xh[k4*4]*w.x + xh[k4*4+1]*w.y + xh[k4*4+2]*w.z + xh[k4*4+3]*w.w;
    }
    const float4* wh = (const float4*)(W_hh + n*128);
#pragma unroll 4
    for (int k4 = 0; k4 < 32; k4++) {
      float4 w = wh[k4];
      acc += xh[64+k4*4]*w.x + xh[64+k4*4+1]*w.y + xh[64+k4*4+2]*w.z + xh[64+k4*4+3]*w.w;
    }
    g4[q] = acc;
  }
  float ig = 1.f / (1.f + expf(-g4[0]));
  float fg = 1.f / (1.f + expf(-g4[1]));
  float gg = tanhf(g4[2]);
  float og = 1.f / (1.f + expf(-g4[3]));
  float c2 = fg * c[b*128 + t] + ig * gg;
  float h2 = og * tanhf(c2);
  c[b*128 + t] = c2;
  h_lstm[b*128 + t] = h2;
}

// rel_pos = h @ W_h2p + b; pred out; lp += rel; din = rel @ W_emb + b_emb
__global__ __launch_bounds__(64) void k_pos(
    const float* __restrict__ h_lstm, float* __restrict__ lp,
    float* __restrict__ din, float* __restrict__ pred,
    const float* __restrict__ W_h2p, const float* __restrict__ b_h2p,
    const float* __restrict__ W_emb, const float* __restrict__ b_emb, int t) {
  int b = blockIdx.x, lane = threadIdx.x;
  float h0 = h_lstm[b*128 + lane];
  float h1 = h_lstm[b*128 + 64 + lane];
  float s0 = h0 * W_h2p[lane*2]     + h1 * W_h2p[(64+lane)*2];
  float s1 = h0 * W_h2p[lane*2 + 1] + h1 * W_h2p[(64+lane)*2 + 1];
#pragma unroll
  for (int off = 32; off > 0; off >>= 1) {
    s0 += __shfl_xor(s0, off);
    s1 += __shfl_xor(s1, off);
  }
  float r0 = s0 + b_h2p[0], r1 = s1 + b_h2p[1];
  if (lane == 0) {
    pred[t*2048 + b*2]     = r0;
    pred[t*2048 + b*2 + 1] = r1;
    lp[b*2]     += r0;
    lp[b*2 + 1] += r1;
  }
  din[b*64 + lane] = r0 * W_emb[lane] + r1 * W_emb[64 + lane] + b_emb[lane];
}

// PW[b,n] = pos_b @ Wc ;  Aa[b,n] = PW + h_b @ W1b + bc
__global__ __launch_bounds__(256) void k_aprep(
    const float* __restrict__ h_lstm, const float* __restrict__ lp,
    const float* __restrict__ W1b, const float* __restrict__ Wc,
    const float* __restrict__ bc, float* __restrict__ PW, float* __restrict__ Aa) {
  int b = blockIdx.x, t = threadIdx.x;
  __shared__ float hs[128];
  if (t < 128) hs[t] = h_lstm[b*128 + t];
  __syncthreads();
  float p0 = lp[b*2], p1 = lp[b*2 + 1];
  for (int n = t; n < 512; n += 256) {
    float acc = 0.f;
#pragma unroll 8
    for (int k = 0; k < 128; k++) acc += hs[k] * W1b[k*512 + n];
    float pw = p0 * Wc[n] + p1 * Wc[512 + n];
    PW[b*512 + n] = pw;
    Aa[b*512 + n] = acc + pw + bc[n];
  }
}

// Fused pool: per scene g, Y[i*32+j,k] = relu(Aa[g*32+j,k] - PW[g*32+i,k]);
// Z = Y @ W_pp2 ; pool[g*32+i,n] = relu(max_j Z + b_pp2[n])
__global__ __launch_bounds__(256) void k_pool(
    const float* __restrict__ Aa, const float* __restrict__ PW,
    const float* __restrict__ Wp2, const float* __restrict__ bp2,
    float* __restrict__ pool) {
  const int nt = blockIdx.x, mt = blockIdx.y, g = blockIdx.z;
  const int tid = threadIdx.x;
  __shared__ float smem[64*68];
  float* As = smem;            // [16][68]
  float* Bs = smem + 16*68;    // [16][68]
  const int tx = tid & 15, ty = tid >> 4;
  const int m0 = mt*64, n0 = nt*64;
  const int sm = tid >> 2, sk4 = (tid & 3) * 4;
  const int pair = m0 + sm;
  const int si = pair >> 5, sj = pair & 31;
  const float* arow = Aa + (g*32 + sj) * 512;
  const float* prow = PW + (g*32 + si) * 512;
  const int bn4 = (tid & 15) * 4, bk = tid >> 4;
  const float* brow = Wp2 + bk*1024 + n0 + bn4;

  float acc[4][4] = {};
  for (int kt = 0; kt < 512; kt += 16) {
    __syncthreads();
    float4 av = *(const float4*)(arow + kt + sk4);
    float4 pv = *(const float4*)(prow + kt + sk4);
    As[(sk4+0)*68 + sm] = fmaxf(av.x - pv.x, 0.f);
    As[(sk4+1)*68 + sm] = fmaxf(av.y - pv.y, 0.f);
    As[(sk4+2)*68 + sm] = fmaxf(av.z - pv.z, 0.f);
    As[(sk4+3)*68 + sm] = fmaxf(av.w - pv.w, 0.f);
    *(float4*)(Bs + bk*68 + bn4) = *(const float4*)(brow + kt*1024);
    __syncthreads();
#pragma unroll
    for (int k = 0; k < 16; k++) {
      float4 a = *(const float4*)(As + k*68 + ty*4);
      float4 b = *(const float4*)(Bs + k*68 + tx*4);
      acc[0][0] += a.x*b.x; acc[0][1] += a.x*b.y; acc[0][2] += a.x*b.z; acc[0][3] += a.x*b.w;
      acc[1][0] += a.y*b.x; acc[1][1] += a.y*b.y; acc[1][2] += a.y*b.z; acc[1][3] += a.y*b.w;
      acc[2][0] += a.z*b.x; acc[2][1] += a.z*b.y; acc[2][2] += a.z*b.z; acc[2][3] += a.z*b.w;
      acc[3][0] += a.w*b.x; acc[3][1] += a.w*b.y; acc[3][2] += a.w*b.z; acc[3][3] += a.w*b.w;
    }
  }
  __syncthreads();
  float* Zs = smem;  // [64][68]
#pragma unroll
  for (int r = 0; r < 4; r++)
    *(float4*)(Zs + (ty*4+r)*68 + tx*4) = make_float4(acc[r][0], acc[r][1], acc[r][2], acc[r][3]);
  __syncthreads();
  if (tid < 128) {
    const int gi = tid >> 6, n = tid & 63;
    float mx = -1e30f;
#pragma unroll 8
    for (int r = 0; r < 32; r++) mx = fmaxf(mx, Zs[(gi*32+r)*68 + n]);
    pool[(g*32 + mt*2 + gi)*1024 + n0 + n] = fmaxf(mx + bp2[n0+n], 0.f);
  }
}

// mid = relu(hcat @ W_m1 + b_m1), hcat = [h_lstm(128) | pool(1024)]
__global__ __launch_bounds__(256) void k_m1(
    const float* __restrict__ hl, const float* __restrict__ pool,
    const float* __restrict__ Wm1, const float* __restrict__ bm1,
    float* __restrict__ mid) {
  const int nt = blockIdx.x, mt = blockIdx.y;
  const int tid = threadIdx.x;
  __shared__ float smem[2*16*68];
  float* As = smem;
  float* Bs = smem + 16*68;
  const int tx = tid & 15, ty = tid >> 4;
  const int m0 = mt*64, n0 = nt*64;
  const int sm = tid >> 2, sk4 = (tid & 3) * 4;
  const int row = m0 + sm;
  const int bn4 = (tid & 15) * 4, bk = tid >> 4;

  float acc[4][4] = {};
  for (int kt = 0; kt < 1152; kt += 16) {
    __syncthreads();
    const int kk = kt + sk4;
    float4 av = (kk < 128) ? *(const float4*)(hl + row*128 + kk)
                           : *(const float4*)(pool + row*1024 + kk - 128);
    As[(sk4+0)*68 + sm] = av.x;
    As[(sk4+1)*68 + sm] = av.y;
    As[(sk4+2)*68 + sm] = av.z;
    As[(sk4+3)*68 + sm] = av.w;
    *(float4*)(Bs + bk*68 + bn4) = *(const float4*)(Wm1 + (kt+bk)*1024 + n0 + bn4);
    __syncthreads();
#pragma unroll
    for (int k = 0; k < 16; k++) {
      float4 a = *(const float4*)(As + k*68 + ty*4);
      float4 b = *(const float4*)(Bs + k*68 + tx*4);
      acc[0][0] += a.x*b.x; acc[0][1] += a.x*b.y; acc[0][2] += a.x*b.z; acc[0][3] += a.x*b.w;
      acc[1][0] += a.y*b.x; acc[1][1] += a.y*b.y; acc[1][2] += a.y*b.z; acc[1][3] += a.y*b.w;
      acc[2][0] += a.z*b.x; acc[2][1] += a.z*b.y; acc[2][2] += a.z*b.z; acc[2][3] += a.z*b.w;
      acc[3][0] += a.w*b.x; acc[3][1] += a.w*b.y; acc[3][2] += a.w*b.z; acc[3][3] += a.w*b.w;
    }
  }
  const float4 bv = *(const float4*)(bm1 + n0 + tx*4);
#pragma unroll
  for (int r = 0; r < 4; r++) {
    float4 o;
    o.x = fmaxf(acc[r][0] + bv.x, 0.f);
    o.y = fmaxf(acc[r][1] + bv.y, 0.f);
    o.z = fmaxf(acc[r][2] + bv.z, 0.f);
    o.w = fmaxf(acc[r][3] + bv.w, 0.f);
    *(float4*)(mid + (m0 + ty*4 + r)*1024 + n0 + tx*4) = o;
  }
}

// h_dec = relu(mid @ W_m2 + b_m2)
__global__ __launch_bounds__(128) void k_m2(
    const float* __restrict__ mid, const float* __restrict__ Wm2,
    const float* __restrict__ bm2, float* __restrict__ h_dec) {
  int b = blockIdx.x, n = threadIdx.x;
  __shared__ float row[1024];
  for (int k = n; k < 1024; k += 128) row[k] = mid[b*1024 + k];
  __syncthreads();
  float acc = bm2[n];
#pragma unroll 8
  for (int k = 0; k < 1024; k++) acc += row[k] * Wm2[k*128 + n];
  h_dec[b*128 + n] = fmaxf(acc, 0.f);
}

__global__ __launch_bounds__(256) void k_hfin(const float* __restrict__ h_dec,
                                              float* __restrict__ out) {
  int idx = blockIdx.x * 256 + threadIdx.x;
  if (idx < 131072) out[24576 + idx] = h_dec[idx];
}

extern "C" void kernel_launch(void* const* d_in, const int* in_sizes, int n_in,
                              void* d_out, int out_size, void* d_ws, size_t ws_size,
                              hipStream_t stream) {
  const float* last_pos = (const float*)d_in[0];
  const float* lpr      = (const float*)d_in[1];
  const float* dh       = (const float*)d_in[2];
  const float* dc       = (const float*)d_in[3];
  // d_in[4]: seq_start_end (unused, uniform groups)
  const float* W_emb = (const float*)d_in[5];
  const float* b_emb = (const float*)d_in[6];
  const float* W_ih  = (const float*)d_in[7];
  const float* b_ih  = (const float*)d_in[8];
  const float* W_hh  = (const float*)d_in[9];
  const float* b_hh  = (const float*)d_in[10];
  const float* W_h2p = (const float*)d_in[11];
  const float* b_h2p = (const float*)d_in[12];
  const float* W_sp  = (const float*)d_in[13];
  const float* b_sp  = (const float*)d_in[14];
  const float* W_pp1 = (const float*)d_in[15];
  const float* b_pp1 = (const float*)d_in[16];
  const float* W_pp2 = (const float*)d_in[17];
  const float* b_pp2 = (const float*)d_in[18];
  const float* W_m1  = (const float*)d_in[19];
  const float* b_m1  = (const float*)d_in[20];
  const float* W_m2  = (const float*)d_in[21];
  const float* b_m2  = (const float*)d_in[22];

  float* ws    = (float*)d_ws;
  float* lp    = ws + OFF_LP;
  float* din   = ws + OFF_DIN;
  float* h_dec = ws + OFF_HDEC;
  float* cst   = ws + OFF_C;
  float* h_l   = ws + OFF_HL;
  float* Wc    = ws + OFF_WC;
  float* bc    = ws + OFF_BC;
  float* PW    = ws + OFF_PW;
  float* Aa    = ws + OFF_AA;
  float* pool  = ws + OFF_POOL;
  float* mid   = ws + OFF_MID;
  float* out   = (float*)d_out;

  k_setup<<<512, 256, 0, stream>>>(last_pos, lpr, dh, dc, W_emb, b_emb, lp, din, h_dec, cst);
  k_wc<<<2, 256, 0, stream>>>(W_sp, b_sp, W_pp1, b_pp1, Wc, bc);

  for (int t = 0; t < T_SEQ; t++) {
    k_lstm<<<1024, 128, 0, stream>>>(din, h_dec, cst, h_l, W_ih, b_ih, W_hh, b_hh);
    k_pos<<<1024, 64, 0, stream>>>(h_l, lp, din, out, W_h2p, b_h2p, W_emb, b_emb, t);
    k_aprep<<<1024, 256, 0, stream>>>(h_l, lp, W_pp1 + 64*512, Wc, bc, PW, Aa);
    dim3 gp(16, 16, 32);
    k_pool<<<gp, 256, 0, stream>>>(Aa, PW, W_pp2, b_pp2, pool);
    dim3 gm(16, 16);
    k_m1<<<gm, 256, 0, stream>>>(h_l, pool, W_m1, b_m1, mid);
    k_m2<<<1024, 128, 0, stream>>>(mid, W_m2, b_m2, h_dec);
  }
  k_hfin<<<512, 256, 0, stream>>>(h_dec, out);
}

// Round 2
// 3008.881 us; speedup vs baseline: 2.3931x; 2.3931x over previous
//
#include <hip/hip_runtime.h>
#include <math.h>

// Problem constants
#define T_SEQ 12
// B=1024, NG=32, G=32, E=64, H=128, PP=512, BOT=1024, MLPD=1024

typedef __bf16 bf16x8 __attribute__((ext_vector_type(8)));
typedef float f32x4 __attribute__((ext_vector_type(4)));
typedef unsigned short u16x8 __attribute__((ext_vector_type(8)));

// Workspace layout (float offsets)
enum : int {
  OFF_LP   = 0,        // [1024,2]
  OFF_DIN  = 2048,     // [1024,64]
  OFF_HDEC = 67584,    // [1024,128]
  OFF_C    = 198656,   // [1024,128]
  OFF_HL   = 329728,   // [1024,128]
  OFF_WC   = 460800,   // [2,512]
  OFF_BC   = 461824,   // [512]
  OFF_PW   = 462336,   // [1024,512]
  OFF_AA   = 986624,   // [1024,512]
  OFF_POOL = 1510912,  // [1024,1024]
  OFF_MID  = 2559488,  // [1024,1024]
  OFF_WP2T = 3608064   // [1024,512] bf16 (262144 floats)
};                     // total 3870208 floats = 15.5 MB

__global__ __launch_bounds__(256) void k_setup(
    const float* __restrict__ last_pos, const float* __restrict__ lpr,
    const float* __restrict__ dh, const float* __restrict__ dc,
    const float* __restrict__ W_emb, const float* __restrict__ b_emb,
    float* __restrict__ lp, float* __restrict__ din,
    float* __restrict__ h_dec, float* __restrict__ c) {
  int idx = blockIdx.x * 256 + threadIdx.x;  // 0..131071
  if (idx < 2048) lp[idx] = last_pos[idx];
  h_dec[idx] = dh[idx];
  c[idx] = dc[idx];
  if (idx < 65536) {
    int b = idx >> 6, e = idx & 63;
    din[idx] = lpr[b*2] * W_emb[e] + lpr[b*2+1] * W_emb[64+e] + b_emb[e];
  }
}

// Wc[r][n] = sum_k W_sp[r,k] * W_pp1[k,n];  bc[n] = sum_k b_sp[k]*W_pp1[k,n] + b_pp1[n]
__global__ __launch_bounds__(256) void k_wc(
    const float* __restrict__ W_sp, const float* __restrict__ b_sp,
    const float* __restrict__ W_pp1, const float* __restrict__ b_pp1,
    float* __restrict__ Wc, float* __restrict__ bc) {
  int n = blockIdx.x * 256 + threadIdx.x;
  if (n >= 512) return;
  float a0 = 0.f, a1 = 0.f, ab = 0.f;
#pragma unroll 8
  for (int k = 0; k < 64; k++) {
    float w = W_pp1[k*512 + n];
    a0 += W_sp[k] * w;
    a1 += W_sp[64+k] * w;
    ab += b_sp[k] * w;
  }
  Wc[n] = a0; Wc[512+n] = a1; bc[n] = ab + b_pp1[n];
}

// Transpose + convert fp32 [R][C] -> bf16 [C][R]
__global__ __launch_bounds__(256) void k_tcvt(
    const float* __restrict__ src, unsigned short* __restrict__ dst,
    int R, int C) {
  __shared__ float t[32][33];
  const int bx = blockIdx.x * 32, by = blockIdx.y * 32;
  const int tx = threadIdx.x & 31, ty = threadIdx.x >> 5;
#pragma unroll
  for (int i = 0; i < 32; i += 8) t[ty+i][tx] = src[(size_t)(by+ty+i)*C + bx+tx];
  __syncthreads();
#pragma unroll
  for (int i = 0; i < 32; i += 8)
    dst[(size_t)(bx+ty+i)*R + by+tx] = __builtin_bit_cast(unsigned short, (__bf16)t[tx][ty+i]);
}

// LSTM cell: one block per batch row, 128 threads (one per h-dim)
__global__ __launch_bounds__(128) void k_lstm(
    const float* __restrict__ din, const float* __restrict__ h_dec,
    float* __restrict__ c, float* __restrict__ h_lstm,
    const float* __restrict__ W_ih, const float* __restrict__ b_ih,
    const float* __restrict__ W_hh, const float* __restrict__ b_hh) {
  int b = blockIdx.x, t = threadIdx.x;
  __shared__ float xh[192];
  if (t < 64) xh[t] = din[b*64 + t];
  xh[64 + t] = h_dec[b*128 + t];
  __syncthreads();
  float g4[4];
#pragma unroll
  for (int q = 0; q < 4; q++) {
    int n = q*128 + t;
    float acc = b_ih[n] + b_hh[n];
    const float4* wi = (const float4*)(W_ih + n*64);
#pragma unroll 4
    for (int k4 = 0; k4 < 16; k4++) {
      float4 w = wi[k4];
      acc += xh[k4*4]*w.x + xh[k4*4+1]*w.y + xh[k4*4+2]*w.z + xh[k4*4+3]*w.w;
    }
    const float4* wh = (const float4*)(W_hh + n*128);
#pragma unroll 4
    for (int k4 = 0; k4 < 32; k4++) {
      float4 w = wh[k4];
      acc += xh[64+k4*4]*w.x + xh[64+k4*4+1]*w.y + xh[64+k4*4+2]*w.z + xh[64+k4*4+3]*w.w;
    }
    g4[q] = acc;
  }
  float ig = 1.f / (1.f + expf(-g4[0]));
  float fg = 1.f / (1.f + expf(-g4[1]));
  float gg = tanhf(g4[2]);
  float og = 1.f / (1.f + expf(-g4[3]));
  float c2 = fg * c[b*128 + t] + ig * gg;
  float h2 = og * tanhf(c2);
  c[b*128 + t] = c2;
  h_lstm[b*128 + t] = h2;
}

// rel_pos = h @ W_h2p + b; pred out; lp += rel; din = rel @ W_emb + b_emb
__global__ __launch_bounds__(64) void k_pos(
    const float* __restrict__ h_lstm, float* __restrict__ lp,
    float* __restrict__ din, float* __restrict__ pred,
    const float* __restrict__ W_h2p, const float* __restrict__ b_h2p,
    const float* __restrict__ W_emb, const float* __restrict__ b_emb, int t) {
  int b = blockIdx.x, lane = threadIdx.x;
  float h0 = h_lstm[b*128 + lane];
  float h1 = h_lstm[b*128 + 64 + lane];
  float s0 = h0 * W_h2p[lane*2]     + h1 * W_h2p[(64+lane)*2];
  float s1 = h0 * W_h2p[lane*2 + 1] + h1 * W_h2p[(64+lane)*2 + 1];
#pragma unroll
  for (int off = 32; off > 0; off >>= 1) {
    s0 += __shfl_xor(s0, off);
    s1 += __shfl_xor(s1, off);
  }
  float r0 = s0 + b_h2p[0], r1 = s1 + b_h2p[1];
  if (lane == 0) {
    pred[t*2048 + b*2]     = r0;
    pred[t*2048 + b*2 + 1] = r1;
    lp[b*2]     += r0;
    lp[b*2 + 1] += r1;
  }
  din[b*64 + lane] = r0 * W_emb[lane] + r1 * W_emb[64 + lane] + b_emb[lane];
}

// PW[b,n] = pos_b @ Wc ;  Aa[b,n] = PW + h_b @ W1b + bc
__global__ __launch_bounds__(256) void k_aprep(
    const float* __restrict__ h_lstm, const float* __restrict__ lp,
    const float* __restrict__ W1b, const float* __restrict__ Wc,
    const float* __restrict__ bc, float* __restrict__ PW, float* __restrict__ Aa) {
  int b = blockIdx.x, t = threadIdx.x;
  __shared__ float hs[128];
  if (t < 128) hs[t] = h_lstm[b*128 + t];
  __syncthreads();
  float p0 = lp[b*2], p1 = lp[b*2 + 1];
  for (int n = t; n < 512; n += 256) {
    float acc = 0.f;
#pragma unroll 8
    for (int k = 0; k < 128; k++) acc += hs[k] * W1b[k*512 + n];
    float pw = p0 * Wc[n] + p1 * Wc[512 + n];
    PW[b*512 + n] = pw;
    Aa[b*512 + n] = acc + pw + bc[n];
  }
}

// --- MFMA fused pool ---
// Per scene g: GEMM rows m = ii*32+j (ii = i-local 0..3, i = mt*4+ii),
// A[m][k] = relu(Aa[g*32+j][k] - PW[g*32+i][k]) in bf16 (built on the fly),
// B[k][n] from pre-transposed bf16 Wp2t[n][k].
// C = A@B, then pool[g*32+i][n] = relu(max_j C + b_pp2[n]).
// LDS tiles [128 rows][64 k] bf16, XOR-swizzled: byte ^= (row&7)<<4.
#define SWZ(r, kb) ((((r) * 128) + (kb)) ^ (((r) & 7) << 4))

__global__ __launch_bounds__(256) void k_pool_mfma(
    const float* __restrict__ Aa, const float* __restrict__ PW,
    const unsigned short* __restrict__ Wp2t, const float* __restrict__ bp2,
    float* __restrict__ pool) {
  const int nt = blockIdx.x;  // 0..7  (128 n-cols each)
  const int mt = blockIdx.y;  // 0..7  (4 i-rows each)
  const int g  = blockIdx.z;  // scene
  const int tid = threadIdx.x;
  const int lane = tid & 63, w = tid >> 6;
  const int wr = w >> 1, wc = w & 1;   // 2x2 waves, 64x64 tile each

  __shared__ __align__(128) char lds[32768];
  char* As = lds;           // [128][64] bf16 swizzled (rows = ii*32+j)
  char* Bs = lds + 16384;   // [128][64] bf16 swizzled (rows = n-local)

  const int srow = tid >> 1;           // 0..127
  const int sk = (tid & 1) * 8;        // bf16 elem offset
  const float* aRow = Aa + (size_t)(g*32 + (srow & 31)) * 512;
  const float* pRow = PW + (size_t)(g*32 + mt*4 + (srow >> 5)) * 512;
  const unsigned short* bRow = Wp2t + (size_t)(nt*128 + srow) * 512;

  f32x4 acc[4][4] = {};

  for (int k0 = 0; k0 < 512; k0 += 64) {
    __syncthreads();
#pragma unroll
    for (int p = 0; p < 4; p++) {
      const int kk = sk + p * 16;  // 0..56
      float4 a0 = *(const float4*)(aRow + k0 + kk);
      float4 a1 = *(const float4*)(aRow + k0 + kk + 4);
      float4 q0 = *(const float4*)(pRow + k0 + kk);
      float4 q1 = *(const float4*)(pRow + k0 + kk + 4);
      bf16x8 y;
      y[0] = (__bf16)fmaxf(a0.x - q0.x, 0.f);
      y[1] = (__bf16)fmaxf(a0.y - q0.y, 0.f);
      y[2] = (__bf16)fmaxf(a0.z - q0.z, 0.f);
      y[3] = (__bf16)fmaxf(a0.w - q0.w, 0.f);
      y[4] = (__bf16)fmaxf(a1.x - q1.x, 0.f);
      y[5] = (__bf16)fmaxf(a1.y - q1.y, 0.f);
      y[6] = (__bf16)fmaxf(a1.z - q1.z, 0.f);
      y[7] = (__bf16)fmaxf(a1.w - q1.w, 0.f);
      *(bf16x8*)(As + SWZ(srow, kk * 2)) = y;
      *(u16x8*)(Bs + SWZ(srow, kk * 2)) = *(const u16x8*)(bRow + k0 + kk);
    }
    __syncthreads();
#pragma unroll
    for (int ks = 0; ks < 2; ks++) {
      const int kb = ks * 64 + (lane >> 4) * 16;
      bf16x8 af[4], bfr[4];
#pragma unroll
      for (int mf = 0; mf < 4; mf++)
        af[mf] = *(const bf16x8*)(As + SWZ(wr*64 + mf*16 + (lane & 15), kb));
#pragma unroll
      for (int nf = 0; nf < 4; nf++)
        bfr[nf] = *(const bf16x8*)(Bs + SWZ(wc*64 + nf*16 + (lane & 15), kb));
#pragma unroll
      for (int mf = 0; mf < 4; mf++)
#pragma unroll
        for (int nf = 0; nf < 4; nf++)
          acc[mf][nf] = __builtin_amdgcn_mfma_f32_16x16x32_bf16(
              af[mf], bfr[nf], acc[mf][nf], 0, 0, 0);
    }
  }

  // Epilogue: per i (2 per wave-row), per n-frag: max over 32 j-rows.
  // C/D layout: col = lane&15, row = (lane>>4)*4 + reg.
#pragma unroll
  for (int isub = 0; isub < 2; isub++) {
#pragma unroll
    for (int nf = 0; nf < 4; nf++) {
      f32x4 v0 = acc[isub*2][nf], v1 = acc[isub*2 + 1][nf];
      float mx = fmaxf(fmaxf(fmaxf(v0[0], v0[1]), fmaxf(v0[2], v0[3])),
                       fmaxf(fmaxf(v1[0], v1[1]), fmaxf(v1[2], v1[3])));
      mx = fmaxf(mx, __shfl_xor(mx, 16));
      mx = fmaxf(mx, __shfl_xor(mx, 32));
      if (lane < 16) {
        const int n = nt*128 + wc*64 + nf*16 + lane;
        pool[(size_t)(g*32 + mt*4 + wr*2 + isub) * 1024 + n] =
            fmaxf(mx + bp2[n], 0.f);
      }
    }
  }
}

// mid = relu(hcat @ W_m1 + b_m1), hcat = [h_lstm(128) | pool(1024)]
__global__ __launch_bounds__(256) void k_m1(
    const float* __restrict__ hl, const float* __restrict__ pool,
    const float* __restrict__ Wm1, const float* __restrict__ bm1,
    float* __restrict__ mid) {
  const int nt = blockIdx.x, mt = blockIdx.y;
  const int tid = threadIdx.x;
  __shared__ float smem[2*16*68];
  float* As = smem;
  float* Bs = smem + 16*68;
  const int tx = tid & 15, ty = tid >> 4;
  const int m0 = mt*64, n0 = nt*64;
  const int sm = tid >> 2, sk4 = (tid & 3) * 4;
  const int row = m0 + sm;
  const int bn4 = (tid & 15) * 4, bk = tid >> 4;

  float acc[4][4] = {};
  for (int kt = 0; kt < 1152; kt += 16) {
    __syncthreads();
    const int kk = kt + sk4;
    float4 av = (kk < 128) ? *(const float4*)(hl + row*128 + kk)
                           : *(const float4*)(pool + row*1024 + kk - 128);
    As[(sk4+0)*68 + sm] = av.x;
    As[(sk4+1)*68 + sm] = av.y;
    As[(sk4+2)*68 + sm] = av.z;
    As[(sk4+3)*68 + sm] = av.w;
    *(float4*)(Bs + bk*68 + bn4) = *(const float4*)(Wm1 + (kt+bk)*1024 + n0 + bn4);
    __syncthreads();
#pragma unroll
    for (int k = 0; k < 16; k++) {
      float4 a = *(const float4*)(As + k*68 + ty*4);
      float4 b = *(const float4*)(Bs + k*68 + tx*4);
      acc[0][0] += a.x*b.x; acc[0][1] += a.x*b.y; acc[0][2] += a.x*b.z; acc[0][3] += a.x*b.w;
      acc[1][0] += a.y*b.x; acc[1][1] += a.y*b.y; acc[1][2] += a.y*b.z; acc[1][3] += a.y*b.w;
      acc[2][0] += a.z*b.x; acc[2][1] += a.z*b.y; acc[2][2] += a.z*b.z; acc[2][3] += a.z*b.w;
      acc[3][0] += a.w*b.x; acc[3][1] += a.w*b.y; acc[3][2] += a.w*b.z; acc[3][3] += a.w*b.w;
    }
  }
  const float4 bv = *(const float4*)(bm1 + n0 + tx*4);
#pragma unroll
  for (int r = 0; r < 4; r++) {
    float4 o;
    o.x = fmaxf(acc[r][0] + bv.x, 0.f);
    o.y = fmaxf(acc[r][1] + bv.y, 0.f);
    o.z = fmaxf(acc[r][2] + bv.z, 0.f);
    o.w = fmaxf(acc[r][3] + bv.w, 0.f);
    *(float4*)(mid + (m0 + ty*4 + r)*1024 + n0 + tx*4) = o;
  }
}

// h_dec = relu(mid @ W_m2 + b_m2)
__global__ __launch_bounds__(128) void k_m2(
    const float* __restrict__ mid, const float* __restrict__ Wm2,
    const float* __restrict__ bm2, float* __restrict__ h_dec) {
  int b = blockIdx.x, n = threadIdx.x;
  __shared__ float row[1024];
  for (int k = n; k < 1024; k += 128) row[k] = mid[b*1024 + k];
  __syncthreads();
  float acc = bm2[n];
#pragma unroll 8
  for (int k = 0; k < 1024; k++) acc += row[k] * Wm2[k*128 + n];
  h_dec[b*128 + n] = fmaxf(acc, 0.f);
}

__global__ __launch_bounds__(256) void k_hfin(const float* __restrict__ h_dec,
                                              float* __restrict__ out) {
  int idx = blockIdx.x * 256 + threadIdx.x;
  if (idx < 131072) out[24576 + idx] = h_dec[idx];
}

extern "C" void kernel_launch(void* const* d_in, const int* in_sizes, int n_in,
                              void* d_out, int out_size, void* d_ws, size_t ws_size,
                              hipStream_t stream) {
  const float* last_pos = (const float*)d_in[0];
  const float* lpr      = (const float*)d_in[1];
  const float* dh       = (const float*)d_in[2];
  const float* dc       = (const float*)d_in[3];
  // d_in[4]: seq_start_end (unused, uniform groups)
  const float* W_emb = (const float*)d_in[5];
  const float* b_emb = (const float*)d_in[6];
  const float* W_ih  = (const float*)d_in[7];
  const float* b_ih  = (const float*)d_in[8];
  const float* W_hh  = (const float*)d_in[9];
  const float* b_hh  = (const float*)d_in[10];
  const float* W_h2p = (const float*)d_in[11];
  const float* b_h2p = (const float*)d_in[12];
  const float* W_sp  = (const float*)d_in[13];
  const float* b_sp  = (const float*)d_in[14];
  const float* W_pp1 = (const float*)d_in[15];
  const float* b_pp1 = (const float*)d_in[16];
  const float* W_pp2 = (const float*)d_in[17];
  const float* b_pp2 = (const float*)d_in[18];
  const float* W_m1  = (const float*)d_in[19];
  const float* b_m1  = (const float*)d_in[20];
  const float* W_m2  = (const float*)d_in[21];
  const float* b_m2  = (const float*)d_in[22];

  float* ws    = (float*)d_ws;
  float* lp    = ws + OFF_LP;
  float* din   = ws + OFF_DIN;
  float* h_dec = ws + OFF_HDEC;
  float* cst   = ws + OFF_C;
  float* h_l   = ws + OFF_HL;
  float* Wc    = ws + OFF_WC;
  float* bc    = ws + OFF_BC;
  float* PW    = ws + OFF_PW;
  float* Aa    = ws + OFF_AA;
  float* pool  = ws + OFF_POOL;
  float* mid   = ws + OFF_MID;
  unsigned short* Wp2t = (unsigned short*)(ws + OFF_WP2T);
  float* out   = (float*)d_out;

  k_setup<<<512, 256, 0, stream>>>(last_pos, lpr, dh, dc, W_emb, b_emb, lp, din, h_dec, cst);
  k_wc<<<2, 256, 0, stream>>>(W_sp, b_sp, W_pp1, b_pp1, Wc, bc);
  {
    dim3 gt(32, 16);  // C/32, R/32 for [512][1024] -> [1024][512]
    k_tcvt<<<gt, 256, 0, stream>>>(W_pp2, Wp2t, 512, 1024);
  }

  for (int t = 0; t < T_SEQ; t++) {
    k_lstm<<<1024, 128, 0, stream>>>(din, h_dec, cst, h_l, W_ih, b_ih, W_hh, b_hh);
    k_pos<<<1024, 64, 0, stream>>>(h_l, lp, din, out, W_h2p, b_h2p, W_emb, b_emb, t);
    k_aprep<<<1024, 256, 0, stream>>>(h_l, lp, W_pp1 + 64*512, Wc, bc, PW, Aa);
    dim3 gp(8, 8, 32);
    k_pool_mfma<<<gp, 256, 0, stream>>>(Aa, PW, Wp2t, b_pp2, pool);
    dim3 gm(16, 16);
    k_m1<<<gm, 256, 0, stream>>>(h_l, pool, W_m1, b_m1, mid);
    k_m2<<<1024, 128, 0, stream>>>(mid, W_m2, b_m2, h_dec);
  }
  k_hfin<<<512, 256, 0, stream>>>(h_dec, out);
}

// Round 3
// 1707.587 us; speedup vs baseline: 4.2169x; 1.7621x over previous
//
#include <hip/hip_runtime.h>
#include <math.h>

#define T_SEQ 12
// B=1024, NG=32, G=32, E=64, H=128, PP=512, BOT=1024, MLPD=1024

typedef __bf16 bf16x8 __attribute__((ext_vector_type(8)));
typedef float f32x4 __attribute__((ext_vector_type(4)));
typedef unsigned short u16x8 __attribute__((ext_vector_type(8)));

static __device__ __forceinline__ unsigned short bf16bits(float x) {
  return __builtin_bit_cast(unsigned short, (__bf16)x);
}

// Workspace layout (float offsets)
enum : int {
  OFF_LP    = 0,        // [1024,2]
  OFF_DIN   = 2048,     // [1024,64]
  OFF_HL    = 67584,    // [1024,128] lstm h (fp32)
  OFF_C     = 198656,   // [1024,128]
  OFF_HDEC  = 329728,   // [1024,128] decoder h (fp32)
  OFF_WC    = 460800,   // [2,512]
  OFF_BC    = 461824,   // [512]
  OFF_PW    = 462336,   // [1024,512]   (aliased by mid)
  OFF_AA    = 986624,   // [1024,512]   (aliased by mid)
  OFF_MID   = 462336,   // [1024,1024] fp32, aliases PW+AA (dead by then)
  OFF_WP2T  = 1510912,  // [1024,512] bf16
  OFF_WM1T  = 1773056,  // [1024,1152] bf16
  OFF_HCATB = 2362880,  // [1024,1152] bf16 (h | pool)
  OFF_WM2T  = 2952704   // [128,1024] fp32
};                      // total 3083776 floats = 12.3 MB

// XOR swizzle: permute 16B slots within each 128B group by row&7
#define SWZP(byte, row) ((byte) ^ (((row) & 7) << 4))

__global__ __launch_bounds__(256) void k_setup(
    const float* __restrict__ last_pos, const float* __restrict__ lpr,
    const float* __restrict__ dh, const float* __restrict__ dc,
    const float* __restrict__ W_emb, const float* __restrict__ b_emb,
    float* __restrict__ lp, float* __restrict__ din,
    float* __restrict__ h_dec, float* __restrict__ c) {
  int idx = blockIdx.x * 256 + threadIdx.x;  // 0..131071
  if (idx < 2048) lp[idx] = last_pos[idx];
  h_dec[idx] = dh[idx];
  c[idx] = dc[idx];
  if (idx < 65536) {
    int b = idx >> 6, e = idx & 63;
    din[idx] = lpr[b*2] * W_emb[e] + lpr[b*2+1] * W_emb[64+e] + b_emb[e];
  }
}

__global__ __launch_bounds__(256) void k_wc(
    const float* __restrict__ W_sp, const float* __restrict__ b_sp,
    const float* __restrict__ W_pp1, const float* __restrict__ b_pp1,
    float* __restrict__ Wc, float* __restrict__ bc) {
  int n = blockIdx.x * 256 + threadIdx.x;
  if (n >= 512) return;
  float a0 = 0.f, a1 = 0.f, ab = 0.f;
#pragma unroll 8
  for (int k = 0; k < 64; k++) {
    float w = W_pp1[k*512 + n];
    a0 += W_sp[k] * w;
    a1 += W_sp[64+k] * w;
    ab += b_sp[k] * w;
  }
  Wc[n] = a0; Wc[512+n] = a1; bc[n] = ab + b_pp1[n];
}

// Transpose + convert fp32 [R][C] -> bf16 [C][R]
__global__ __launch_bounds__(256) void k_tcvt(
    const float* __restrict__ src, unsigned short* __restrict__ dst,
    int R, int C) {
  __shared__ float t[32][33];
  const int bx = blockIdx.x * 32, by = blockIdx.y * 32;
  const int tx = threadIdx.x & 31, ty = threadIdx.x >> 5;
#pragma unroll
  for (int i = 0; i < 32; i += 8) t[ty+i][tx] = src[(size_t)(by+ty+i)*C + bx+tx];
  __syncthreads();
#pragma unroll
  for (int i = 0; i < 32; i += 8)
    dst[(size_t)(bx+ty+i)*R + by+tx] = bf16bits(t[tx][ty+i]);
}

// Transpose fp32 [R][C] -> fp32 [C][R]  (for W_m2 [1024][128] -> [128][1024])
__global__ __launch_bounds__(256) void k_t32(
    const float* __restrict__ src, float* __restrict__ dst, int R, int C) {
  __shared__ float t[32][33];
  const int bx = blockIdx.x * 32, by = blockIdx.y * 32;
  const int tx = threadIdx.x & 31, ty = threadIdx.x >> 5;
#pragma unroll
  for (int i = 0; i < 32; i += 8) t[ty+i][tx] = src[(size_t)(by+ty+i)*C + bx+tx];
  __syncthreads();
#pragma unroll
  for (int i = 0; i < 32; i += 8)
    dst[(size_t)(bx+ty+i)*R + by+tx] = t[tx][ty+i];
}

// LSTM: 8 rows/block, 512 threads (one gate-col each)
__global__ __launch_bounds__(512) void k_lstm2(
    const float* __restrict__ din, const float* __restrict__ h_dec,
    float* __restrict__ c, float* __restrict__ h_l,
    unsigned short* __restrict__ hcatB,
    const float* __restrict__ W_ih, const float* __restrict__ b_ih,
    const float* __restrict__ W_hh, const float* __restrict__ b_hh) {
  const int b0 = blockIdx.x * 8;
  const int tid = threadIdx.x;
  __shared__ float xh[8*192];
  __shared__ float gl[8*512];
  for (int i = tid; i < 1536; i += 512) {
    int r = i / 192, k = i - r*192;
    xh[i] = (k < 64) ? din[(b0+r)*64 + k] : h_dec[(b0+r)*128 + k - 64];
  }
  __syncthreads();
  const int n = tid;
  float acc[8];
  {
    float bias = b_ih[n] + b_hh[n];
#pragma unroll
    for (int r = 0; r < 8; r++) acc[r] = bias;
  }
  const float4* wi = (const float4*)(W_ih + n*64);
#pragma unroll 4
  for (int k4 = 0; k4 < 16; k4++) {
    float4 wv = wi[k4];
#pragma unroll
    for (int r = 0; r < 8; r++) {
      const float* x = xh + r*192 + k4*4;
      acc[r] += x[0]*wv.x + x[1]*wv.y + x[2]*wv.z + x[3]*wv.w;
    }
  }
  const float4* wh = (const float4*)(W_hh + n*128);
#pragma unroll 4
  for (int k4 = 0; k4 < 32; k4++) {
    float4 wv = wh[k4];
#pragma unroll
    for (int r = 0; r < 8; r++) {
      const float* x = xh + r*192 + 64 + k4*4;
      acc[r] += x[0]*wv.x + x[1]*wv.y + x[2]*wv.z + x[3]*wv.w;
    }
  }
#pragma unroll
  for (int r = 0; r < 8; r++) gl[r*512 + n] = acc[r];
  __syncthreads();
  for (int o = tid; o < 1024; o += 512) {
    int r = o >> 7, hh = o & 127;
    float ig = gl[r*512 + hh],       fg = gl[r*512 + 128 + hh];
    float gg = gl[r*512 + 256 + hh], og = gl[r*512 + 384 + hh];
    ig = 1.f/(1.f+expf(-ig)); fg = 1.f/(1.f+expf(-fg));
    gg = tanhf(gg);           og = 1.f/(1.f+expf(-og));
    int row = b0 + r;
    float c2 = fg * c[row*128 + hh] + ig * gg;
    float h2 = og * tanhf(c2);
    c[row*128 + hh] = c2;
    h_l[row*128 + hh] = h2;
    hcatB[(size_t)row*1152 + hh] = bf16bits(h2);
  }
}

// Fused pos + A-prep: 8 rows/block, 512 threads
__global__ __launch_bounds__(512) void k_aprep2(
    const float* __restrict__ h_l, float* __restrict__ lp,
    float* __restrict__ din, float* __restrict__ pred,
    const float* __restrict__ W_h2p, const float* __restrict__ b_h2p,
    const float* __restrict__ W_emb, const float* __restrict__ b_emb,
    const float* __restrict__ W1b, const float* __restrict__ Wc,
    const float* __restrict__ bc,
    float* __restrict__ PW, float* __restrict__ Aa, int t) {
  const int b0 = blockIdx.x * 8;
  const int tid = threadIdx.x;
  __shared__ float hs[8*128];
  __shared__ float relS[16], curS[16];
  for (int i = tid; i < 1024; i += 512)
    hs[i] = h_l[(size_t)(b0 + (i >> 7))*128 + (i & 127)];
  __syncthreads();
  if (tid < 256) {
    int r = tid >> 5, col = (tid >> 4) & 1, l16 = tid & 15;
    float s = 0.f;
    for (int k = l16; k < 128; k += 16) s += hs[r*128 + k] * W_h2p[k*2 + col];
#pragma unroll
    for (int off = 8; off > 0; off >>= 1) s += __shfl_xor(s, off);
    if (l16 == 0) {
      float rel = s + b_h2p[col];
      float old = lp[(b0+r)*2 + col];
      relS[r*2 + col] = rel;
      curS[r*2 + col] = old + rel;
      lp[(b0+r)*2 + col] = old + rel;
      pred[t*2048 + (b0+r)*2 + col] = rel;
    }
  }
  __syncthreads();
  {
    int r = tid >> 6, e = tid & 63;
    din[(b0+r)*64 + e] = relS[r*2]*W_emb[e] + relS[r*2+1]*W_emb[64+e] + b_emb[e];
  }
  const int n = tid;
  float acc[8] = {0.f,0.f,0.f,0.f,0.f,0.f,0.f,0.f};
#pragma unroll 4
  for (int k = 0; k < 128; k++) {
    float wv = W1b[k*512 + n];
#pragma unroll
    for (int r = 0; r < 8; r++) acc[r] += hs[r*128 + k] * wv;
  }
  float wc0 = Wc[n], wc1 = Wc[512+n], bcv = bc[n];
#pragma unroll
  for (int r = 0; r < 8; r++) {
    float pw = curS[r*2]*wc0 + curS[r*2+1]*wc1;
    PW[(size_t)(b0+r)*512 + n] = pw;
    Aa[(size_t)(b0+r)*512 + n] = acc[r] + pw + bcv;
  }
}

// --- A-resident fused pool GEMM ---
// Block (mt, g): A rows m = ii*32+j (i = mt*4+ii), full K=512, in 128KB LDS.
// Loop nt(8) x k0(8): stream 16KB B-chunks of Wp2t. Epilogue: max over j,
// bias, relu, write bf16 into hcatB pool columns.
__global__ __launch_bounds__(256) void k_pool2(
    const float* __restrict__ Aa, const float* __restrict__ PW,
    const unsigned short* __restrict__ Wp2t, const float* __restrict__ bp2,
    unsigned short* __restrict__ hcatB) {
  const int mt = blockIdx.x;   // 0..7
  const int g  = blockIdx.y;   // 0..31
  const int tid = threadIdx.x;
  const int lane = tid & 63, w = tid >> 6;
  const int wr = w >> 1, wc = w & 1;   // 2x2 waves, 64m x 64n each

  __shared__ __align__(128) char lds[147456];
  char* As = lds;            // [128 rows][1024 B] swizzled
  char* Bs = lds + 131072;   // [128 rows][128 B] swizzled

  // A construction (once): thread: row = tid>>1, k-half = (tid&1)*256
  {
    const int r = tid >> 1, kh = (tid & 1) * 256;
    const int j = r & 31, ii = r >> 5;
    const float* aRow = Aa + (size_t)(g*32 + j) * 512;
    const float* pRow = PW + (size_t)(g*32 + mt*4 + ii) * 512;
#pragma unroll 4
    for (int kk = 0; kk < 256; kk += 8) {
      float4 a0 = *(const float4*)(aRow + kh + kk);
      float4 a1 = *(const float4*)(aRow + kh + kk + 4);
      float4 p0 = *(const float4*)(pRow + kh + kk);
      float4 p1 = *(const float4*)(pRow + kh + kk + 4);
      bf16x8 y;
      y[0] = (__bf16)fmaxf(a0.x - p0.x, 0.f);
      y[1] = (__bf16)fmaxf(a0.y - p0.y, 0.f);
      y[2] = (__bf16)fmaxf(a0.z - p0.z, 0.f);
      y[3] = (__bf16)fmaxf(a0.w - p0.w, 0.f);
      y[4] = (__bf16)fmaxf(a1.x - p1.x, 0.f);
      y[5] = (__bf16)fmaxf(a1.y - p1.y, 0.f);
      y[6] = (__bf16)fmaxf(a1.z - p1.z, 0.f);
      y[7] = (__bf16)fmaxf(a1.w - p1.w, 0.f);
      *(bf16x8*)(As + SWZP(r*1024 + (kh + kk)*2, r)) = y;
    }
  }

  const int brow = tid >> 1, bhalf = tid & 1;
  u16x8 breg[4], bnext[4];
  {
    const unsigned short* src = Wp2t + (size_t)brow*512 + bhalf*32;  // q=0
#pragma unroll
    for (int i = 0; i < 4; i++) breg[i] = *(const u16x8*)(src + i*8);
  }

  for (int nt = 0; nt < 8; nt++) {
    f32x4 acc[4][4] = {};
    for (int k0 = 0; k0 < 8; k0++) {
      // write current B chunk
#pragma unroll
      for (int i = 0; i < 4; i++)
        *(u16x8*)(Bs + SWZP(brow*128 + bhalf*64 + i*16, brow)) = breg[i];
      // prefetch next chunk
      int q = nt*8 + k0 + 1;
      if (q < 64) {
        const unsigned short* src =
            Wp2t + (size_t)((q >> 3)*128 + brow)*512 + (q & 7)*64 + bhalf*32;
#pragma unroll
        for (int i = 0; i < 4; i++) bnext[i] = *(const u16x8*)(src + i*8);
      }
      __syncthreads();
#pragma unroll
      for (int ks = 0; ks < 2; ks++) {
        const int klocal = ks*32 + (lane >> 4)*8;   // bf16 elems
        bf16x8 af[4], bf[4];
#pragma unroll
        for (int mf = 0; mf < 4; mf++) {
          int row = wr*64 + mf*16 + (lane & 15);
          af[mf] = *(const bf16x8*)(As + SWZP(row*1024 + (k0*64 + klocal)*2, row));
        }
#pragma unroll
        for (int nf = 0; nf < 4; nf++) {
          int rn = wc*64 + nf*16 + (lane & 15);
          bf[nf] = *(const bf16x8*)(Bs + SWZP(rn*128 + klocal*2, rn));
        }
#pragma unroll
        for (int mf = 0; mf < 4; mf++)
#pragma unroll
          for (int nf = 0; nf < 4; nf++)
            acc[mf][nf] = __builtin_amdgcn_mfma_f32_16x16x32_bf16(
                af[mf], bf[nf], acc[mf][nf], 0, 0, 0);
      }
      __syncthreads();
#pragma unroll
      for (int i = 0; i < 4; i++) breg[i] = bnext[i];
    }
    // epilogue for this nt: max over j (m-direction), bias, relu -> hcatB
#pragma unroll
    for (int isub = 0; isub < 2; isub++) {
#pragma unroll
      for (int nf = 0; nf < 4; nf++) {
        f32x4 v0 = acc[isub*2][nf], v1 = acc[isub*2 + 1][nf];
        float mx = fmaxf(fmaxf(fmaxf(v0[0], v0[1]), fmaxf(v0[2], v0[3])),
                         fmaxf(fmaxf(v1[0], v1[1]), fmaxf(v1[2], v1[3])));
        mx = fmaxf(mx, __shfl_xor(mx, 16));
        mx = fmaxf(mx, __shfl_xor(mx, 32));
        if (lane < 16) {
          int n = nt*128 + wc*64 + nf*16 + lane;
          int i = mt*4 + wr*2 + isub;
          hcatB[(size_t)(g*32 + i)*1152 + 128 + n] =
              bf16bits(fmaxf(mx + bp2[n], 0.f));
        }
      }
    }
  }
}

// mid = relu(hcatB @ Wm1t^T + b_m1): MFMA, BM=128 BN=64 BK=128
__global__ __launch_bounds__(256) void k_m1m(
    const unsigned short* __restrict__ hcatB,
    const unsigned short* __restrict__ Wm1t,
    const float* __restrict__ bm1, float* __restrict__ mid) {
  const int nt = blockIdx.x;   // 0..15
  const int mt = blockIdx.y;   // 0..7
  const int tid = threadIdx.x, lane = tid & 63, w = tid >> 6;
  const int wr = w >> 1, wc = w & 1;   // wave: 64m x 32n
  __shared__ __align__(128) char lds[49152];
  char* As = lds;            // [128][256B]
  char* Bs = lds + 32768;    // [64][256B]

  const int rA = tid >> 1, hA = tid & 1;
  const int rB = tid >> 2, qB = tid & 3;
  u16x8 apre[8], bpre[4];
  {
    const unsigned short* sa = hcatB + (size_t)(mt*128 + rA)*1152 + hA*64;
#pragma unroll
    for (int i = 0; i < 8; i++) apre[i] = *(const u16x8*)(sa + i*8);
    const unsigned short* sb = Wm1t + (size_t)(nt*64 + rB)*1152 + qB*32;
#pragma unroll
    for (int i = 0; i < 4; i++) bpre[i] = *(const u16x8*)(sb + i*8);
  }

  f32x4 acc[4][2] = {};
  for (int c = 0; c < 9; c++) {
    if (c) __syncthreads();
#pragma unroll
    for (int i = 0; i < 8; i++)
      *(u16x8*)(As + SWZP(rA*256 + hA*128 + i*16, rA)) = apre[i];
#pragma unroll
    for (int i = 0; i < 4; i++)
      *(u16x8*)(Bs + SWZP(rB*256 + qB*64 + i*16, rB)) = bpre[i];
    if (c + 1 < 9) {
      const unsigned short* sa = hcatB + (size_t)(mt*128 + rA)*1152 + (c+1)*128 + hA*64;
#pragma unroll
      for (int i = 0; i < 8; i++) apre[i] = *(const u16x8*)(sa + i*8);
      const unsigned short* sb = Wm1t + (size_t)(nt*64 + rB)*1152 + (c+1)*128 + qB*32;
#pragma unroll
      for (int i = 0; i < 4; i++) bpre[i] = *(const u16x8*)(sb + i*8);
    }
    __syncthreads();
#pragma unroll
    for (int ks = 0; ks < 4; ks++) {
      const int kb = (ks*32 + (lane >> 4)*8) * 2;
      bf16x8 af[4], bf[2];
#pragma unroll
      for (int mf = 0; mf < 4; mf++) {
        int row = wr*64 + mf*16 + (lane & 15);
        af[mf] = *(const bf16x8*)(As + SWZP(row*256 + kb, row));
      }
#pragma unroll
      for (int nf = 0; nf < 2; nf++) {
        int rn = wc*32 + nf*16 + (lane & 15);
        bf[nf] = *(const bf16x8*)(Bs + SWZP(rn*256 + kb, rn));
      }
#pragma unroll
      for (int mf = 0; mf < 4; mf++)
#pragma unroll
        for (int nf = 0; nf < 2; nf++)
          acc[mf][nf] = __builtin_amdgcn_mfma_f32_16x16x32_bf16(
              af[mf], bf[nf], acc[mf][nf], 0, 0, 0);
    }
  }
#pragma unroll
  for (int mf = 0; mf < 4; mf++)
#pragma unroll
    for (int nf = 0; nf < 2; nf++) {
      int col = nt*64 + wc*32 + nf*16 + (lane & 15);
      float bv = bm1[col];
#pragma unroll
      for (int r = 0; r < 4; r++) {
        int row = mt*128 + wr*64 + mf*16 + (lane >> 4)*4 + r;
        mid[(size_t)row*1024 + col] = fmaxf(acc[mf][nf][r] + bv, 0.f);
      }
    }
}

// h_dec = relu(mid @ W_m2 + b_m2), fp32, Wm2t pre-transposed [128][1024]
__global__ __launch_bounds__(256) void k_m2f(
    const float* __restrict__ mid, const float* __restrict__ Wm2t,
    const float* __restrict__ bm2, float* __restrict__ h_dec) {
  const int b0 = blockIdx.x * 4;
  const int tid = threadIdx.x;
  __shared__ float ms[4*1024];
  {
    const float4* src = (const float4*)(mid + (size_t)b0*1024);
    float4* dst = (float4*)ms;
    for (int i = tid; i < 1024; i += 256) dst[i] = src[i];
  }
  __syncthreads();
  const int n = tid & 127, rq = tid >> 7;   // 2 rows per thread
  float a0 = 0.f, a1 = 0.f;
  const float4* wrow = (const float4*)(Wm2t + (size_t)n*1024);
#pragma unroll 4
  for (int k4 = 0; k4 < 256; k4++) {
    float4 wv = wrow[k4];
    const float* m0 = ms + (rq*2)*1024 + k4*4;
    const float* m1 = ms + (rq*2 + 1)*1024 + k4*4;
    a0 += m0[0]*wv.x + m0[1]*wv.y + m0[2]*wv.z + m0[3]*wv.w;
    a1 += m1[0]*wv.x + m1[1]*wv.y + m1[2]*wv.z + m1[3]*wv.w;
  }
  float bv = bm2[n];
  h_dec[(size_t)(b0 + rq*2)*128 + n]     = fmaxf(a0 + bv, 0.f);
  h_dec[(size_t)(b0 + rq*2 + 1)*128 + n] = fmaxf(a1 + bv, 0.f);
}

__global__ __launch_bounds__(256) void k_hfin(const float* __restrict__ h_dec,
                                              float* __restrict__ out) {
  int idx = blockIdx.x * 256 + threadIdx.x;
  if (idx < 131072) out[24576 + idx] = h_dec[idx];
}

extern "C" void kernel_launch(void* const* d_in, const int* in_sizes, int n_in,
                              void* d_out, int out_size, void* d_ws, size_t ws_size,
                              hipStream_t stream) {
  const float* last_pos = (const float*)d_in[0];
  const float* lpr      = (const float*)d_in[1];
  const float* dh       = (const float*)d_in[2];
  const float* dc       = (const float*)d_in[3];
  const float* W_emb = (const float*)d_in[5];
  const float* b_emb = (const float*)d_in[6];
  const float* W_ih  = (const float*)d_in[7];
  const float* b_ih  = (const float*)d_in[8];
  const float* W_hh  = (const float*)d_in[9];
  const float* b_hh  = (const float*)d_in[10];
  const float* W_h2p = (const float*)d_in[11];
  const float* b_h2p = (const float*)d_in[12];
  const float* W_sp  = (const float*)d_in[13];
  const float* b_sp  = (const float*)d_in[14];
  const float* W_pp1 = (const float*)d_in[15];
  const float* b_pp1 = (const float*)d_in[16];
  const float* W_pp2 = (const float*)d_in[17];
  const float* b_pp2 = (const float*)d_in[18];
  const float* W_m1  = (const float*)d_in[19];
  const float* b_m1  = (const float*)d_in[20];
  const float* W_m2  = (const float*)d_in[21];
  const float* b_m2  = (const float*)d_in[22];

  float* ws    = (float*)d_ws;
  float* lp    = ws + OFF_LP;
  float* din   = ws + OFF_DIN;
  float* h_l   = ws + OFF_HL;
  float* cst   = ws + OFF_C;
  float* h_dec = ws + OFF_HDEC;
  float* Wc    = ws + OFF_WC;
  float* bc    = ws + OFF_BC;
  float* PW    = ws + OFF_PW;
  float* Aa    = ws + OFF_AA;
  float* mid   = ws + OFF_MID;
  unsigned short* Wp2t  = (unsigned short*)(ws + OFF_WP2T);
  unsigned short* Wm1t  = (unsigned short*)(ws + OFF_WM1T);
  unsigned short* hcatB = (unsigned short*)(ws + OFF_HCATB);
  float* Wm2t  = ws + OFF_WM2T;
  float* out   = (float*)d_out;

  k_setup<<<512, 256, 0, stream>>>(last_pos, lpr, dh, dc, W_emb, b_emb, lp, din, h_dec, cst);
  k_wc<<<2, 256, 0, stream>>>(W_sp, b_sp, W_pp1, b_pp1, Wc, bc);
  { dim3 gt(32, 16); k_tcvt<<<gt, 256, 0, stream>>>(W_pp2, Wp2t, 512, 1024); }
  { dim3 gt(32, 36); k_tcvt<<<gt, 256, 0, stream>>>(W_m1, Wm1t, 1152, 1024); }
  { dim3 gt(4, 32);  k_t32<<<gt, 256, 0, stream>>>(W_m2, Wm2t, 1024, 128); }

  for (int t = 0; t < T_SEQ; t++) {
    k_lstm2<<<128, 512, 0, stream>>>(din, h_dec, cst, h_l, hcatB,
                                     W_ih, b_ih, W_hh, b_hh);
    k_aprep2<<<128, 512, 0, stream>>>(h_l, lp, din, out, W_h2p, b_h2p,
                                      W_emb, b_emb, W_pp1 + 64*512, Wc, bc,
                                      PW, Aa, t);
    { dim3 gp(8, 32); k_pool2<<<gp, 256, 0, stream>>>(Aa, PW, Wp2t, b_pp2, hcatB); }
    { dim3 gm(16, 8); k_m1m<<<gm, 256, 0, stream>>>(hcatB, Wm1t, b_m1, mid); }
    k_m2f<<<256, 256, 0, stream>>>(mid, Wm2t, b_m2, h_dec);
  }
  k_hfin<<<512, 256, 0, stream>>>(h_dec, out);
}